// Round 1
// baseline (243.689 us; speedup 1.0000x reference)
//
#include <hip/hip_runtime.h>

// Problem constants (from reference):
//   x: [16384, 8192] fp32, c: [4096, 2, 2] fp32
//   out[b, 2n+o] = x[b,2n]*W[n,0,o] + x[b,2n+1]*W[n,1,o]
//   W[n,m,o] = softmax over m of c[n,:,o] = sigmoid(c[n,m,o] - c[n,1-m,o])
#define ELI_BATCH     16384
#define ELI_LAYER_IN  8192
#define ELI_NCHUNK    (ELI_LAYER_IN / 4)   // 2048 float4 per row
#define ELI_CBLOCKS   (ELI_NCHUNK / 256)   // 8 blocks cover the columns
#define ELI_ROWG      256                  // row groups
#define ELI_ROWS_PG   (ELI_BATCH / ELI_ROWG) // 64 rows per group

__global__ __launch_bounds__(256, 8)
void EfficientLearnableInterconnect_33913061769291_kernel(
        const float* __restrict__ x,
        const float* __restrict__ c,
        float* __restrict__ out) {
    // Fixed column chunk per thread: one float4 = columns [4*chunk, 4*chunk+3]
    // = blocks 2*chunk and 2*chunk+1 (2 inputs / 2 outputs each).
    const int chunk = (blockIdx.x & (ELI_CBLOCKS - 1)) * 256 + threadIdx.x; // 0..2047
    const int rowg  = blockIdx.x / ELI_CBLOCKS;                             // 0..255
    const int row0  = rowg * ELI_ROWS_PG;

    // c[n] as float4: (c[n,0,0], c[n,0,1], c[n,1,0], c[n,1,1])
    const float4 c0 = ((const float4*)c)[2 * chunk];
    const float4 c1 = ((const float4*)c)[2 * chunk + 1];

    // wBMO: block B, input m=M, output o=O.  w[m][o] = sigmoid(c[m,o]-c[1-m,o])
    const float w000 = 1.f / (1.f + expf(c0.z - c0.x));
    const float w010 = 1.f / (1.f + expf(c0.x - c0.z));
    const float w001 = 1.f / (1.f + expf(c0.w - c0.y));
    const float w011 = 1.f / (1.f + expf(c0.y - c0.w));
    const float w100 = 1.f / (1.f + expf(c1.z - c1.x));
    const float w110 = 1.f / (1.f + expf(c1.x - c1.z));
    const float w101 = 1.f / (1.f + expf(c1.w - c1.y));
    const float w111 = 1.f / (1.f + expf(c1.y - c1.w));

    const float4* xp = (const float4*)x + (size_t)row0 * ELI_NCHUNK + chunk;
    float4*       op = (float4*)out     + (size_t)row0 * ELI_NCHUNK + chunk;

    #pragma unroll 4
    for (int r = 0; r < ELI_ROWS_PG; ++r) {
        const float4 v = xp[(size_t)r * ELI_NCHUNK];
        float4 o;
        o.x = v.x * w000 + v.y * w010;  // block 2c,   out o=0
        o.y = v.x * w001 + v.y * w011;  // block 2c,   out o=1
        o.z = v.z * w100 + v.w * w110;  // block 2c+1, out o=0
        o.w = v.z * w101 + v.w * w111;  // block 2c+1, out o=1
        op[(size_t)r * ELI_NCHUNK] = o;
    }
}

extern "C" void kernel_launch(void* const* d_in, const int* in_sizes, int n_in,
                              void* d_out, int out_size, void* d_ws, size_t ws_size,
                              hipStream_t stream) {
    const float* x = (const float*)d_in[0];
    const float* c = (const float*)d_in[1];
    float* out = (float*)d_out;

    const dim3 grid(ELI_CBLOCKS * ELI_ROWG);  // 2048 blocks
    const dim3 block(256);
    EfficientLearnableInterconnect_33913061769291_kernel<<<grid, block, 0, stream>>>(x, c, out);
}

// Round 3
// 220.514 us; speedup vs baseline: 1.1051x; 1.1051x over previous
//
#include <hip/hip_runtime.h>

// out[b, 2n+o] = x[b,2n]*W[n,0,o] + x[b,2n+1]*W[n,1,o]
// W[n,m,o] = softmax_m(c[n,:,o]) = sigmoid(c[n,m,o] - c[n,1-m,o])
// Pure streaming op: x read once (512 MiB), out written once (512 MiB),
// weights loop-invariant per thread. Memory-bound; target = copy ceiling.
#define ELI_BATCH     16384
#define ELI_LAYER_IN  8192
#define ELI_NCHUNK    (ELI_LAYER_IN / 4)     // 2048 float4 per row
#define ELI_CBLOCKS   (ELI_NCHUNK / 256)     // 8 blocks cover the columns
#define ELI_ROWG      256                    // row groups
#define ELI_ROWS_PG   (ELI_BATCH / ELI_ROWG) // 64 rows per group

typedef float f32x4 __attribute__((ext_vector_type(4)));  // native vector: OK for nontemporal builtins

__global__ __launch_bounds__(256, 8)
void EfficientLearnableInterconnect_33913061769291_kernel(
        const float* __restrict__ x,
        const float* __restrict__ c,
        float* __restrict__ out) {
    const int chunk = (blockIdx.x & (ELI_CBLOCKS - 1)) * 256 + threadIdx.x; // 0..2047
    const int rowg  = blockIdx.x / ELI_CBLOCKS;                             // 0..255
    const int row0  = rowg * ELI_ROWS_PG;

    // c[n] as f32x4: (c[n,0,0], c[n,0,1], c[n,1,0], c[n,1,1])
    const f32x4 c0 = ((const f32x4*)c)[2 * chunk];
    const f32x4 c1 = ((const f32x4*)c)[2 * chunk + 1];

    const float w000 = 1.f / (1.f + __expf(c0.z - c0.x));
    const float w010 = 1.f / (1.f + __expf(c0.x - c0.z));
    const float w001 = 1.f / (1.f + __expf(c0.w - c0.y));
    const float w011 = 1.f / (1.f + __expf(c0.y - c0.w));
    const float w100 = 1.f / (1.f + __expf(c1.z - c1.x));
    const float w110 = 1.f / (1.f + __expf(c1.x - c1.z));
    const float w101 = 1.f / (1.f + __expf(c1.w - c1.y));
    const float w111 = 1.f / (1.f + __expf(c1.y - c1.w));

    const f32x4* __restrict__ xp = (const f32x4*)x + (size_t)row0 * ELI_NCHUNK + chunk;
    f32x4* __restrict__       op = (f32x4*)out     + (size_t)row0 * ELI_NCHUNK + chunk;

    #pragma unroll 8
    for (int r = 0; r < ELI_ROWS_PG; ++r) {
        const f32x4 v = __builtin_nontemporal_load(xp);
        f32x4 o;
        o.x = v.x * w000 + v.y * w010;
        o.y = v.x * w001 + v.y * w011;
        o.z = v.z * w100 + v.w * w110;
        o.w = v.z * w101 + v.w * w111;
        __builtin_nontemporal_store(o, op);
        xp += ELI_NCHUNK;
        op += ELI_NCHUNK;
    }
}

extern "C" void kernel_launch(void* const* d_in, const int* in_sizes, int n_in,
                              void* d_out, int out_size, void* d_ws, size_t ws_size,
                              hipStream_t stream) {
    const float* x = (const float*)d_in[0];
    const float* c = (const float*)d_in[1];
    float* out = (float*)d_out;

    const dim3 grid(ELI_CBLOCKS * ELI_ROWG);  // 2048 blocks
    const dim3 block(256);
    EfficientLearnableInterconnect_33913061769291_kernel<<<grid, block, 0, stream>>>(x, c, out);
}